// Round 6
// baseline (23833.928 us; speedup 1.0000x reference)
//
#include <hip/hip_runtime.h>
#include <math.h>

#define T_STEPS 16384
#define IN_DIM  14
#define H_DIM   100
#define G_DIM   300   // 3*H

typedef float f2v  __attribute__((ext_vector_type(2)));
typedef float f16v __attribute__((ext_vector_type(16)));

// Workspace layout (floats): [0,8192) h1 ring (64 slots x 128), [8192,16384) h2 ring,
// [16384, 16384+T*300) gi0.
#define RING_SLOTS 64
#define SLOT_F     128
#define GI0_OFS    16384

// ---------------- Phase 0: gi0[t][j] = b_ih0[j] + sum_k x[t][k]*w_ih0[j][k] ----------------
__global__ void gi0_kernel(const float* __restrict__ x,
                           const float* __restrict__ w_ih0,
                           const float* __restrict__ b_ih0,
                           float* __restrict__ gi0) {
    int e = blockIdx.x * blockDim.x + threadIdx.x;
    if (e >= T_STEPS * G_DIM) return;
    int t = e / G_DIM;
    int j = e - t * G_DIM;
    const float* xr = x + t * IN_DIM;
    const float* wr = w_ih0 + j * IN_DIM;
    float acc = b_ih0[j];
    #pragma unroll
    for (int k = 0; k < IN_DIM; ++k) acc = fmaf(xr[k], wr[k], acc);
    gi0[e] = acc;
}

// ---------------- Phase 1: persistent single-workgroup sequential GRU ----------------
// HISTORY (do not regress):
//  R1-R5: every attempt to hold >=200 weight floats/thread hit a hard 128-VGPR
//  allocator cap (attributes waves_per_eu(1)/(2,2), launch_bounds, pins all
//  failed; pins caused memory spills). R6: fit UNDER the cap -- 1 row/thread
//  (100 weight VGPRs) across 960 threads, and distribute h via SGPRs
//  (s_dcache_inv + s_load from an L2-resident ring) so the dot phase has no
//  LDS traffic (b128 broadcast ~6.5cyc x waves x 25 was the next wall).
__global__ __attribute__((amdgpu_flat_work_group_size(960, 960), amdgpu_waves_per_eu(4)))
void gru_seq_kernel(const float* __restrict__ gi0,
                    const float* __restrict__ ring1,   // h1 ring (read)
                    const float* __restrict__ ring2,   // h2 ring (read)
                    float* __restrict__ ring1w,
                    float* __restrict__ ring2w,
                    const float* __restrict__ w_hh0,
                    const float* __restrict__ b_hh0,
                    const float* __restrict__ w_ih1,
                    const float* __restrict__ b_ih1,
                    const float* __restrict__ w_hh1,
                    const float* __restrict__ b_hh1,
                    const float* __restrict__ fc_w,
                    const float* __restrict__ fc_b,
                    float* __restrict__ out) {
    __shared__ __align__(16) float hbuf[256];      // h1 at [0,100), h2 at [128,228)
    __shared__ __align__(16) float gh[3 * G_DIM];  // [0,300) gh0, [300,600) gi1, [600,900) gh1

    const int tid  = threadIdx.x;
    const int lane = tid & 63;
    const int wid  = tid >> 6;          // 0..14
    const int gsel = wid / 5;           // 0: w_hh0 (vs h1), 1: w_ih1 (vs h1), 2: w_hh1 (vs h2)
    const int rig  = (wid - gsel * 5) * 64 + lane;   // row in group, 0..319
    const bool active = rig < G_DIM;
    const int row  = active ? rig : (G_DIM - 1);

    const float* wmat; const float* bvec;
    if (gsel == 0)      { wmat = w_hh0; bvec = b_hh0; }
    else if (gsel == 1) { wmat = w_ih1; bvec = b_ih1; }
    else                { wmat = w_hh1; bvec = b_hh1; }
    const float bias = bvec[row];
    const int ghidx = gsel * G_DIM + rig;

    // ---- 50 named f2 weight values (100 VGPRs), literal indices, pinned ----
    f2v w_0,w_1,w_2,w_3,w_4,w_5,w_6,w_7,w_8,w_9,w_10,w_11,w_12,w_13,w_14,w_15,w_16,w_17,
        w_18,w_19,w_20,w_21,w_22,w_23,w_24,w_25,w_26,w_27,w_28,w_29,w_30,w_31,w_32,w_33,
        w_34,w_35,w_36,w_37,w_38,w_39,w_40,w_41,w_42,w_43,w_44,w_45,w_46,w_47,w_48,w_49;
    {
        const float4* wp = reinterpret_cast<const float4*>(wmat + (size_t)row * H_DIM);
        #define LOADW(k, a, b) { float4 A = wp[k]; w_##a.x = A.x; w_##a.y = A.y; w_##b.x = A.z; w_##b.y = A.w; }
        LOADW(0,0,1)   LOADW(1,2,3)   LOADW(2,4,5)   LOADW(3,6,7)   LOADW(4,8,9)
        LOADW(5,10,11) LOADW(6,12,13) LOADW(7,14,15) LOADW(8,16,17) LOADW(9,18,19)
        LOADW(10,20,21) LOADW(11,22,23) LOADW(12,24,25) LOADW(13,26,27) LOADW(14,28,29)
        LOADW(15,30,31) LOADW(16,32,33) LOADW(17,34,35) LOADW(18,36,37) LOADW(19,38,39)
        LOADW(20,40,41) LOADW(21,42,43) LOADW(22,44,45) LOADW(23,46,47) LOADW(24,48,49)
        #undef LOADW
    }
    #define PIN(k) asm volatile("" : "+v"(w_##k));
    PIN(0) PIN(1) PIN(2) PIN(3) PIN(4) PIN(5) PIN(6) PIN(7) PIN(8) PIN(9)
    PIN(10) PIN(11) PIN(12) PIN(13) PIN(14) PIN(15) PIN(16) PIN(17) PIN(18) PIN(19)
    PIN(20) PIN(21) PIN(22) PIN(23) PIN(24) PIN(25) PIN(26) PIN(27) PIN(28) PIN(29)
    PIN(30) PIN(31) PIN(32) PIN(33) PIN(34) PIN(35) PIN(36) PIN(37) PIN(38) PIN(39)
    PIN(40) PIN(41) PIN(42) PIN(43) PIN(44) PIN(45) PIN(46) PIN(47) PIN(48) PIN(49)
    #undef PIN

    // init LDS h and ring slots read before first production
    if (tid < 256) hbuf[tid] = 0.0f;
    if (tid < 128) {
        ring1w[63 * SLOT_F + tid] = 0.0f;   // h1[-1]
        ring2w[63 * SLOT_F + tid] = 0.0f;   // h2[-2]
        ring2w[tid] = 0.0f;                 // slot 0: h2[-1] (gate skipped at i=0)
    }
    __syncthreads();

    // uniform ring base for this wave
    const int gu = __builtin_amdgcn_readfirstlane(gsel);
    const float* myring = (gu == 2) ? ring2 : ring1;

    for (int i = 0; i <= T_STEPS; ++i) {
        // Prefetch gi0 row i (h1 gate threads)
        float gr = 0.f, gz = 0.f, gn = 0.f;
        if (tid < H_DIM && i < T_STEPS) {
            const float* p = gi0 + (size_t)i * G_DIM + tid;
            gr = p[0]; gz = p[H_DIM]; gn = p[2 * H_DIM];
        }

        // ---- h into SGPRs: 2 chunks of 50 floats ----
        const int slot = (i - 1) & (RING_SLOTS - 1);
        const float* hptr = myring + (slot << 7);
        __builtin_amdgcn_s_dcache_inv();
        f16v ha, hb, hc; f2v hd;
        asm volatile(
            "s_load_dwordx16 %0, %4, 0x0\n\t"
            "s_load_dwordx16 %1, %4, 0x40\n\t"
            "s_load_dwordx16 %2, %4, 0x80\n\t"
            "s_load_dwordx2  %3, %4, 0xc0\n\t"
            "s_waitcnt lgkmcnt(0)"
            : "=&s"(ha), "=&s"(hb), "=&s"(hc), "=&s"(hd)
            : "s"(hptr)
            : "memory");

        f2v acc_a, acc_b;
        acc_a.x = bias; acc_a.y = 0.0f;
        acc_b.x = 0.0f; acc_b.y = 0.0f;
        #define FMA(ACC, WK, HV, J) { f2v hp; hp.x = (HV)[2*(J)]; hp.y = (HV)[2*(J)+1]; ACC += WK * hp; }
        FMA(acc_a, w_0, ha, 0) FMA(acc_a, w_1, ha, 1) FMA(acc_a, w_2, ha, 2) FMA(acc_a, w_3, ha, 3)
        FMA(acc_a, w_4, ha, 4) FMA(acc_a, w_5, ha, 5) FMA(acc_a, w_6, ha, 6) FMA(acc_a, w_7, ha, 7)
        FMA(acc_a, w_8, hb, 0) FMA(acc_a, w_9, hb, 1) FMA(acc_a, w_10, hb, 2) FMA(acc_a, w_11, hb, 3)
        FMA(acc_a, w_12, hb, 4) FMA(acc_a, w_13, hb, 5) FMA(acc_a, w_14, hb, 6) FMA(acc_a, w_15, hb, 7)
        FMA(acc_a, w_16, hc, 0) FMA(acc_a, w_17, hc, 1) FMA(acc_a, w_18, hc, 2) FMA(acc_a, w_19, hc, 3)
        FMA(acc_a, w_20, hc, 4) FMA(acc_a, w_21, hc, 5) FMA(acc_a, w_22, hc, 6) FMA(acc_a, w_23, hc, 7)
        FMA(acc_a, w_24, hd, 0)

        const float* hptr2 = hptr + 50;
        f16v ea, eb, ec; f2v ed;
        asm volatile(
            "s_load_dwordx16 %0, %4, 0x0\n\t"
            "s_load_dwordx16 %1, %4, 0x40\n\t"
            "s_load_dwordx16 %2, %4, 0x80\n\t"
            "s_load_dwordx2  %3, %4, 0xc0\n\t"
            "s_waitcnt lgkmcnt(0)"
            : "=&s"(ea), "=&s"(eb), "=&s"(ec), "=&s"(ed)
            : "s"(hptr2)
            : "memory");

        FMA(acc_b, w_25, ea, 0) FMA(acc_b, w_26, ea, 1) FMA(acc_b, w_27, ea, 2) FMA(acc_b, w_28, ea, 3)
        FMA(acc_b, w_29, ea, 4) FMA(acc_b, w_30, ea, 5) FMA(acc_b, w_31, ea, 6) FMA(acc_b, w_32, ea, 7)
        FMA(acc_b, w_33, eb, 0) FMA(acc_b, w_34, eb, 1) FMA(acc_b, w_35, eb, 2) FMA(acc_b, w_36, eb, 3)
        FMA(acc_b, w_37, eb, 4) FMA(acc_b, w_38, eb, 5) FMA(acc_b, w_39, eb, 6) FMA(acc_b, w_40, eb, 7)
        FMA(acc_b, w_41, ec, 0) FMA(acc_b, w_42, ec, 1) FMA(acc_b, w_43, ec, 2) FMA(acc_b, w_44, ec, 3)
        FMA(acc_b, w_45, ec, 4) FMA(acc_b, w_46, ec, 5) FMA(acc_b, w_47, ec, 6) FMA(acc_b, w_48, ec, 7)
        FMA(acc_b, w_49, ed, 0)
        #undef FMA

        if (active) gh[ghidx] = (acc_a.x + acc_a.y) + (acc_b.x + acc_b.y);
        __syncthreads();

        // ---- Gate phase ----
        const int wslot = i & (RING_SLOTS - 1);
        if (tid < H_DIM) {
            if (i < T_STEPS) {   // h1[i]
                float r = 1.0f / (1.0f + expf(-(gr + gh[tid])));
                float z = 1.0f / (1.0f + expf(-(gz + gh[H_DIM + tid])));
                float n = tanhf(gn + r * gh[2 * H_DIM + tid]);
                float hp = hbuf[tid];
                float hn = (1.0f - z) * n + z * hp;
                hbuf[tid] = hn;
                ring1w[wslot * SLOT_F + tid] = hn;
            }
        } else if (tid >= 256 && tid < 256 + H_DIM) {
            if (i >= 1) {        // h2[i-1]
                int j = tid - 256;
                float r = 1.0f / (1.0f + expf(-(gh[G_DIM + j] + gh[2 * G_DIM + j])));
                float z = 1.0f / (1.0f + expf(-(gh[G_DIM + H_DIM + j] + gh[2 * G_DIM + H_DIM + j])));
                float n = tanhf(gh[G_DIM + 2 * H_DIM + j] + r * gh[2 * G_DIM + 2 * H_DIM + j]);
                float hp = hbuf[128 + j];
                float hn = (1.0f - z) * n + z * hp;
                hbuf[128 + j] = hn;
                ring2w[wslot * SLOT_F + j] = hn;
            }
        }
        __syncthreads();
    }

    // FC epilogue: out = fc_b + fc_w . h2[T-1]
    if (tid < 64) {
        float s = 0.0f;
        for (int j = tid; j < H_DIM; j += 64) s = fmaf(fc_w[j], hbuf[128 + j], s);
        #pragma unroll
        for (int off = 32; off > 0; off >>= 1) s += __shfl_down(s, off);
        if (tid == 0) out[0] = s + fc_b[0];
    }
}

extern "C" void kernel_launch(void* const* d_in, const int* in_sizes, int n_in,
                              void* d_out, int out_size, void* d_ws, size_t ws_size,
                              hipStream_t stream) {
    const float* x     = (const float*)d_in[0];
    const float* w_ih0 = (const float*)d_in[1];
    const float* w_hh0 = (const float*)d_in[2];
    const float* b_ih0 = (const float*)d_in[3];
    const float* b_hh0 = (const float*)d_in[4];
    const float* w_ih1 = (const float*)d_in[5];
    const float* w_hh1 = (const float*)d_in[6];
    const float* b_ih1 = (const float*)d_in[7];
    const float* b_hh1 = (const float*)d_in[8];
    const float* fc_w  = (const float*)d_in[9];
    const float* fc_b  = (const float*)d_in[10];
    float* out = (float*)d_out;

    float* ws   = (float*)d_ws;
    float* r1   = ws;               // h1 ring: 64 x 128
    float* r2   = ws + 8192;        // h2 ring
    float* gi0  = ws + GI0_OFS;     // T*300 floats

    const int total = T_STEPS * G_DIM;
    gi0_kernel<<<(total + 255) / 256, 256, 0, stream>>>(x, w_ih0, b_ih0, gi0);
    gru_seq_kernel<<<1, 960, 0, stream>>>(gi0, r1, r2, r1, r2,
                                          w_hh0, b_hh0, w_ih1, b_ih1,
                                          w_hh1, b_hh1, fc_w, fc_b, out);
}